// Round 1
// baseline (3129.303 us; speedup 1.0000x reference)
//
#include <hip/hip_runtime.h>

// Problem constants
constexpr int B   = 16;
constexpr int N   = 768;
constexpr int FIN = 56;
constexpr int D   = 140;
constexpr int L   = 4;
constexpr int DF  = 128;
constexpr int NN  = N * N;        // 589824
constexpr int BND = B * N * D;    // 1720320
constexpr int BNN = B * NN;       // 9437184

// ---------------------------------------------------------------------------
// K1: x = c_hs @ W_emb   [B*N,56] @ [56,140]
__global__ __launch_bounds__(256) void k_embed(const float* __restrict__ chs,
                                               const float* __restrict__ Wemb,
                                               float* __restrict__ x) {
    int idx = blockIdx.x * 256 + threadIdx.x;
    if (idx >= BND) return;
    int d  = idx % D;
    int bn = idx / D;
    const float* row = chs + bn * FIN;
    float acc = 0.f;
#pragma unroll 8
    for (int f = 0; f < FIN; ++f) acc += row[f] * Wemb[f * D + d];
    x[idx] = acc;
}

// ---------------------------------------------------------------------------
// K2: adj2 = formulate(c_adjs2)  (elementwise, mask from valid/num_atoms)
__global__ __launch_bounds__(256) void k_adj2(const float* __restrict__ a2,
                                              const int* __restrict__ valid,
                                              const int* __restrict__ natoms,
                                              const float* __restrict__ mu,
                                              const float* __restrict__ dev,
                                              float* __restrict__ out) {
    int idx = blockIdx.x * 256 + threadIdx.x;
    if (idx >= BNN) return;
    int b   = idx / NN;
    int rem = idx - b * NN;
    int i   = rem / N;
    int j   = rem - i * N;
    float a = a2[idx];
    int vi = valid[b * N + i];
    int vj = valid[b * N + j];
    int n  = natoms[b];
    bool mask = (vi && !vj && (j < n)) || (vj && !vi && (i < n));
    float dmu = a - mu[0];
    float g = (a <= 10.f) ? expf(-dmu * dmu / dev[0]) : 0.f;
    out[idx] = mask ? g : a;
}

// ---------------------------------------------------------------------------
// K3: out[bn,d] = in[bn,:] @ W[:,d] (+ bias)   — [B*N,140]@[140,140]
__global__ __launch_bounds__(256) void k_linear140(const float* __restrict__ in,
                                                   const float* __restrict__ W,
                                                   const float* __restrict__ bias,
                                                   float* __restrict__ out) {
    int idx = blockIdx.x * 256 + threadIdx.x;
    if (idx >= BND) return;
    int d  = idx % D;
    int bn = idx / D;
    const float* row = in + bn * D;
    float acc = bias ? bias[d] : 0.f;
#pragma unroll 4
    for (int k = 0; k < D; ++k) acc += row[k] * W[k * D + d];
    out[idx] = acc;
}

// ---------------------------------------------------------------------------
// K4: E[b,j,k] = hA[b,j,:]·h[b,k,:] + hA[b,k,:]·h[b,j,:]  (symmetric).
// Upper-triangle 32x32 tiles only; mirror write. Two LDS phases to stay <64KB.
__global__ __launch_bounds__(256) void k_e(const float* __restrict__ h,
                                           const float* __restrict__ hA,
                                           float* __restrict__ E) {
    int tj = blockIdx.x, tk = blockIdx.y, b = blockIdx.z;
    if (tj > tk) return;
    __shared__ float s0[32][141];  // rows of j-tile
    __shared__ float s1[32][141];  // rows of k-tile
    int tid   = threadIdx.x;
    int col   = tid & 31;
    int rbase = tid >> 5;
    int j0 = tj * 32, k0 = tk * 32;
    const float* hb = h  + (size_t)b * N * D;
    const float* ab = hA + (size_t)b * N * D;

    float acc[4] = {0.f, 0.f, 0.f, 0.f};

    // phase 1: acc += hA[j]·h[k]
    for (int idx = tid; idx < 32 * D; idx += 256) {
        int r = idx / D, c = idx - r * D;
        s0[r][c] = ab[(size_t)(j0 + r) * D + c];
        s1[r][c] = hb[(size_t)(k0 + r) * D + c];
    }
    __syncthreads();
#pragma unroll 4
    for (int kk = 0; kk < D; ++kk) {
        float v = s1[col][kk];
#pragma unroll
        for (int q = 0; q < 4; ++q) acc[q] += s0[rbase + q * 8][kk] * v;
    }
    __syncthreads();

    // phase 2: acc += h[j]·hA[k]
    for (int idx = tid; idx < 32 * D; idx += 256) {
        int r = idx / D, c = idx - r * D;
        s0[r][c] = hb[(size_t)(j0 + r) * D + c];
        s1[r][c] = ab[(size_t)(k0 + r) * D + c];
    }
    __syncthreads();
#pragma unroll 4
    for (int kk = 0; kk < D; ++kk) {
        float v = s1[col][kk];
#pragma unroll
        for (int q = 0; q < 4; ++q) acc[q] += s0[rbase + q * 8][kk] * v;
    }

    float* Eb = E + (size_t)b * NN;
#pragma unroll
    for (int q = 0; q < 4; ++q) {
        int j = j0 + rbase + q * 8;
        int k = k0 + col;
        float v = acc[q];
        Eb[(size_t)j * N + k] = v;
        Eb[(size_t)k * N + j] = v;   // mirror (same value on diagonal tile)
    }
}

// ---------------------------------------------------------------------------
// K5: column softmax over axis j of masked E, times adj.
// ATT[b,j,k] = softmax_j( adj>0 ? E : -9e15 ) * adj
// Block: 64 columns, 4 j-slices of threads. Two passes (online m,s; then write).
__global__ __launch_bounds__(256) void k_softmax(const float* __restrict__ E,
                                                 const float* __restrict__ adj,
                                                 float* __restrict__ ATT) {
    int b    = blockIdx.y;
    int lane = threadIdx.x & 63;
    int js   = threadIdx.x >> 6;   // 0..3
    int k    = blockIdx.x * 64 + lane;
    const float* Eb = E   + (size_t)b * NN;
    const float* Ab = adj + (size_t)b * NN;
    float*       Tb = ATT + (size_t)b * NN;

    float m = -3.0e38f, s = 0.f;
#pragma unroll 4
    for (int j = js; j < N; j += 4) {
        float av = Ab[(size_t)j * N + k];
        float ev = Eb[(size_t)j * N + k];
        float x  = (av > 0.f) ? ev : -9e15f;
        float nm = fmaxf(m, x);
        s = s * __expf(m - nm) + __expf(x - nm);
        m = nm;
    }
    __shared__ float sm[4][64], ss[4][64];
    sm[js][lane] = m;
    ss[js][lane] = s;
    __syncthreads();
    if (js == 0) {
        float M = sm[0][lane], S = ss[0][lane];
#pragma unroll
        for (int q = 1; q < 4; ++q) {
            float m2 = sm[q][lane], s2 = ss[q][lane];
            float nm = fmaxf(M, m2);
            S = S * __expf(M - nm) + s2 * __expf(m2 - nm);
            M = nm;
        }
        sm[0][lane] = M;
        ss[0][lane] = 1.f / S;
    }
    __syncthreads();
    float M = sm[0][lane], invS = ss[0][lane];
#pragma unroll 4
    for (int j = js; j < N; j += 4) {
        float av = Ab[(size_t)j * N + k];
        float ev = Eb[(size_t)j * N + k];
        float x  = (av > 0.f) ? ev : -9e15f;
        Tb[(size_t)j * N + k] = __expf(x - M) * invS * av;
    }
}

// ---------------------------------------------------------------------------
// K6: hp = relu(ATT @ h)   [768,768]@[768,140], 32x32-d tiles
__global__ __launch_bounds__(256) void k_ath(const float* __restrict__ ATT,
                                             const float* __restrict__ h,
                                             float* __restrict__ hp) {
    int ti = blockIdx.x, td = blockIdx.y, b = blockIdx.z;
    __shared__ float sA[32][33];
    __shared__ float sH[32][33];
    int tid   = threadIdx.x;
    int col   = tid & 31;
    int rbase = tid >> 5;
    int i0 = ti * 32, d0 = td * 32;
    const float* Tb = ATT + (size_t)b * NN;
    const float* hb = h + (size_t)b * N * D;
    float acc[4] = {0.f, 0.f, 0.f, 0.f};
    int d = d0 + col;
    for (int jt = 0; jt < N / 32; ++jt) {
        int j0 = jt * 32;
#pragma unroll
        for (int q = 0; q < 4; ++q) {
            int r = rbase + q * 8;
            sA[r][col] = Tb[(size_t)(i0 + r) * N + (j0 + col)];
            sH[r][col] = (d < D) ? hb[(size_t)(j0 + r) * D + d] : 0.f;
        }
        __syncthreads();
#pragma unroll 8
        for (int jj = 0; jj < 32; ++jj) {
            float hv = sH[jj][col];
#pragma unroll
            for (int q = 0; q < 4; ++q) acc[q] += sA[rbase + q * 8][jj] * hv;
        }
        __syncthreads();
    }
    if (d < D) {
#pragma unroll
        for (int q = 0; q < 4; ++q) {
            int i = i0 + rbase + q * 8;
            hp[(size_t)b * N * D + (size_t)i * D + d] = fmaxf(acc[q], 0.f);
        }
    }
}

// ---------------------------------------------------------------------------
// K7: gate combine. mode 0: g1 = coeff*x+(1-coeff)*hp
//                   mode 1: x  = (coeff*x+(1-coeff)*hp) - g1   (in place)
__global__ __launch_bounds__(64) void k_gate(const float* __restrict__ x,
                                             const float* __restrict__ hp,
                                             const float* __restrict__ gw,
                                             const float* __restrict__ gb,
                                             float* __restrict__ g1,
                                             float* __restrict__ xout,
                                             int mode) {
    int row  = blockIdx.x;           // 0..B*N-1
    int lane = threadIdx.x;
    const float* xr = x  + (size_t)row * D;
    const float* hr = hp + (size_t)row * D;
    float part = 0.f;
    for (int d = lane; d < D; d += 64) part += xr[d] * gw[d] + hr[d] * gw[D + d];
#pragma unroll
    for (int off = 32; off; off >>= 1) part += __shfl_xor(part, off);
    float c = 1.f / (1.f + __expf(-(part + gb[0])));
    for (int d = lane; d < D; d += 64) {
        float v = c * xr[d] + (1.f - c) * hr[d];
        if (mode == 0) g1[(size_t)row * D + d] = v;
        else           xout[(size_t)row * D + d] = v - g1[(size_t)row * D + d];
    }
}

// ---------------------------------------------------------------------------
// K8: ragged sum pool + 4-layer MLP + sigmoid. One block per batch.
__global__ __launch_bounds__(256) void k_final(const float* __restrict__ x,
                                               const int* __restrict__ natoms,
                                               const float* __restrict__ w0, const float* __restrict__ b0,
                                               const float* __restrict__ w1, const float* __restrict__ b1,
                                               const float* __restrict__ w2, const float* __restrict__ b2,
                                               const float* __restrict__ w3, const float* __restrict__ b3,
                                               float* __restrict__ out) {
    int b   = blockIdx.x;
    int tid = threadIdx.x;
    __shared__ float pred[D];
    __shared__ float h0[DF], h1[DF], h2[DF];
    int n = natoms[b];
    if (tid < D) {
        float acc = 0.f;
        const float* xb = x + (size_t)b * N * D;
        for (int r = 0; r < n; ++r) acc += xb[(size_t)r * D + tid];
        pred[tid] = acc;
    }
    __syncthreads();
    if (tid < DF) {
        float acc = b0[tid];
#pragma unroll 4
        for (int i = 0; i < D; ++i) acc += pred[i] * w0[i * DF + tid];
        h0[tid] = fmaxf(acc, 0.f);
    }
    __syncthreads();
    if (tid < DF) {
        float acc = b1[tid];
#pragma unroll 4
        for (int i = 0; i < DF; ++i) acc += h0[i] * w1[i * DF + tid];
        h1[tid] = fmaxf(acc, 0.f);
    }
    __syncthreads();
    if (tid < DF) {
        float acc = b2[tid];
#pragma unroll 4
        for (int i = 0; i < DF; ++i) acc += h1[i] * w2[i * DF + tid];
        h2[tid] = fmaxf(acc, 0.f);
    }
    __syncthreads();
    if (tid == 0) {
        float acc = b3[0];
        for (int i = 0; i < DF; ++i) acc += h2[i] * w3[i];
        out[b] = 1.f / (1.f + expf(-acc));
    }
}

// ---------------------------------------------------------------------------
extern "C" void kernel_launch(void* const* d_in, const int* in_sizes, int n_in,
                              void* d_out, int out_size, void* d_ws, size_t ws_size,
                              hipStream_t stream) {
    const float* c_hs  = (const float*)d_in[0];
    const float* adj1  = (const float*)d_in[1];
    const float* c_a2  = (const float*)d_in[2];
    const int*   valid = (const int*)d_in[3];
    const int*   nat   = (const int*)d_in[4];
    const float* Wemb  = (const float*)d_in[5];
    const float* gatW  = (const float*)d_in[6];
    const float* gatWb = (const float*)d_in[7];
    const float* gatA  = (const float*)d_in[8];
    const float* gatgw = (const float*)d_in[9];
    const float* gatgb = (const float*)d_in[10];
    const float* w0 = (const float*)d_in[11];
    const float* b0 = (const float*)d_in[12];
    const float* w1 = (const float*)d_in[13];
    const float* b1 = (const float*)d_in[14];
    const float* w2 = (const float*)d_in[15];
    const float* b2 = (const float*)d_in[16];
    const float* w3 = (const float*)d_in[17];
    const float* b3 = (const float*)d_in[18];
    const float* mu  = (const float*)d_in[19];
    const float* dev = (const float*)d_in[20];
    float* out = (float*)d_out;

    float* ws    = (float*)d_ws;
    float* adj2f = ws;                  // BNN
    float* Ebuf  = adj2f + BNN;         // BNN
    float* ATT   = Ebuf + BNN;          // BNN
    float* x     = ATT + BNN;           // BND
    float* h     = x + BND;             // BND
    float* hA    = h + BND;             // BND
    float* hp    = hA + BND;            // BND
    float* g1    = hp + BND;            // BND
    // total: 3*BNN + 5*BND floats = 147.7 MB

    k_embed<<<(BND + 255) / 256, 256, 0, stream>>>(c_hs, Wemb, x);
    k_adj2<<<(BNN + 255) / 256, 256, 0, stream>>>(c_a2, valid, nat, mu, dev, adj2f);

    for (int l = 0; l < L; ++l) {
        const float* Wl  = gatW + (size_t)l * D * D;
        const float* Wbl = gatWb + (size_t)l * D;
        const float* Al  = gatA + (size_t)l * D * D;
        const float* gwl = gatgw + (size_t)l * 2 * D;
        const float* gbl = gatgb + l;

        k_linear140<<<(BND + 255) / 256, 256, 0, stream>>>(x, Wl, Wbl, h);
        k_linear140<<<(BND + 255) / 256, 256, 0, stream>>>(h, Al, nullptr, hA);
        k_e<<<dim3(N / 32, N / 32, B), 256, 0, stream>>>(h, hA, Ebuf);

        // gate 1: adj = c_adjs1
        k_softmax<<<dim3(N / 64, B), 256, 0, stream>>>(Ebuf, adj1, ATT);
        k_ath<<<dim3(N / 32, (D + 31) / 32, B), 256, 0, stream>>>(ATT, h, hp);
        k_gate<<<B * N, 64, 0, stream>>>(x, hp, gwl, gbl, g1, nullptr, 0);

        // gate 2: adj = adj2f; x = gate2 - gate1 (in place)
        k_softmax<<<dim3(N / 64, B), 256, 0, stream>>>(Ebuf, adj2f, ATT);
        k_ath<<<dim3(N / 32, (D + 31) / 32, B), 256, 0, stream>>>(ATT, h, hp);
        k_gate<<<B * N, 64, 0, stream>>>(x, hp, gwl, gbl, g1, x, 1);
    }

    k_final<<<B, 256, 0, stream>>>(x, nat, w0, b0, w1, b1, w2, b2, w3, b3, out);
}